// Round 9
// baseline (466.597 us; speedup 1.0000x reference)
//
#include <hip/hip_runtime.h>
#include <hip/hip_bf16.h>

namespace {
constexpr int S = 2048;
constexpr int D = 64;
constexpr float QSCALE = 0.18033688011112042f;  // (1/sqrt(64)) * log2(e)
constexpr int SMEM_BYTES = 53248;  // 52 KB -> 3 blocks/CU (leaves a dispatch queue)

using f32x4 = __attribute__((ext_vector_type(4))) float;
using bf16x8 = __attribute__((ext_vector_type(8))) short;

__device__ __forceinline__ short f2bf(float f) {
  return __builtin_bit_cast(short, __float2bfloat16(f));  // native RNE cvt
}
#if __has_builtin(__builtin_amdgcn_exp2f)
__device__ __forceinline__ float exp2_fast(float x) { return __builtin_amdgcn_exp2f(x); }
#else
__device__ __forceinline__ float exp2_fast(float x) { return exp2f(x); }
#endif
__device__ __forceinline__ void bar_lds() {  // lgkm-only barrier: vmem stays in flight
  asm volatile("s_waitcnt lgkmcnt(0)" ::: "memory");
  __builtin_amdgcn_s_barrier();
}
}  // namespace

// One block = (bh, q-tile pair (2m, 2m+1)).
// Phase 1: A(qt0) -> l0, O0.   Phase 2: A(qt1) with B(qt0) piggybacked on the
// SAME kf fragments (recompute costs 8 MFMA + 16 exp + 4 stores per tile, no
// staging/barriers).   Phase 3: standalone B(qt1) + all zero-fill.
__global__ __launch_bounds__(256, 3) void attn_pair(const float* __restrict__ qg,
                                                    const float* __restrict__ kg,
                                                    const float* __restrict__ vg,
                                                    float* __restrict__ outg) {
  extern __shared__ short smem[];
  short* const kb0 = smem;              // K[j][d] bf16 swizzled, dbuf
  short* const kb1 = smem + 4096;
  short* const vb0 = smem + 8192;       // V^T[d][j] bf16 swizzled, dbuf
  short* const vb1 = smem + 12288;

  const int tid = threadIdx.x;
  const int w = tid >> 6, lane = tid & 63, lg = lane >> 4, lr = lane & 15;
  short* const psc = smem + 16384 + w * 1024;  // per-wave p~ scratch (16x64)

  // XCD-chunked; within XCD: pair index ascending = biggest blocks dispatched first
  const int u = blockIdx.x;            // 1024 blocks
  const int xcd = u & 7;
  const int t = u >> 3;                // [0,128) per XCD
  const int bh = xcd * 8 + (t & 7);
  const int mmi = 15 - (t >> 3);       // 15..0 -> qt0 = 30..0 (big first)
  const int qt0 = 2 * mmi, qt1 = qt0 + 1;
  const int NT0 = qt0 + 1, NT1 = qt0 + 2;

  const size_t bh_off = (size_t)bh * S * D;
  float* const og = outg;
  float* const a_base = outg + (size_t)64 * S * D + (size_t)bh * S * S;
  const int asw = (lr & 7) << 3;

  const int igl0 = qt0 * 64 + w * 16 + lr;
  const int igl1 = qt1 * 64 + w * 16 + lr;

  // ---- Q B-fragments for both q-tiles (col i = lr-row, k = d), QSCALE folded ----
  bf16x8 qf0[2], qf1[2];
#pragma unroll
  for (int kh = 0; kh < 2; ++kh) {
    const float* qp0 = qg + bh_off + (size_t)igl0 * D + kh * 32 + lg * 8;
    const float* qp1 = qg + bh_off + (size_t)igl1 * D + kh * 32 + lg * 8;
    f32x4 a0 = *(const f32x4*)qp0, a1 = *(const f32x4*)(qp0 + 4);
    f32x4 b0 = *(const f32x4*)qp1, b1 = *(const f32x4*)(qp1 + 4);
    bf16x8 f0, f1;
#pragma unroll
    for (int e = 0; e < 4; ++e) {
      f0[e] = f2bf(a0[e] * QSCALE); f0[e + 4] = f2bf(a1[e] * QSCALE);
      f1[e] = f2bf(b0[e] * QSCALE); f1[e + 4] = f2bf(b1[e] * QSCALE);
    }
    qf0[kh] = f0; qf1[kh] = f1;
  }

  const int krow = tid >> 2, kc = (tid & 3) * 16;
  const int kswz = (krow & 7) << 3;
  const int vj = tid & 63, vd0 = (tid >> 6) * 16;

  f32x4 ka[4], va[4];
  f32x4 oacc[4];

#define LOAD_KT(kt_) do { const float* kp_ = kg + bh_off + (size_t)((kt_) * 64 + krow) * D + kc; \
    ka[0] = *(const f32x4*)(kp_);     ka[1] = *(const f32x4*)(kp_ + 4);                          \
    ka[2] = *(const f32x4*)(kp_ + 8); ka[3] = *(const f32x4*)(kp_ + 12); } while (0)
#define LOAD_VT(kt_) do { const float* vp_ = vg + bh_off + (size_t)((kt_) * 64 + vj) * D + vd0;  \
    va[0] = *(const f32x4*)(vp_);     va[1] = *(const f32x4*)(vp_ + 4);                          \
    va[2] = *(const f32x4*)(vp_ + 8); va[3] = *(const f32x4*)(vp_ + 12); } while (0)
#define STAGE_K(dst_) do { bf16x8 kb_;                                                           \
    _Pragma("unroll") for (int e = 0; e < 4; ++e) { kb_[e] = f2bf(ka[0][e]); kb_[e+4] = f2bf(ka[1][e]); } \
    *(bf16x8*)(&(dst_)[(krow * 64 + kc) ^ kswz]) = kb_;                                          \
    _Pragma("unroll") for (int e = 0; e < 4; ++e) { kb_[e] = f2bf(ka[2][e]); kb_[e+4] = f2bf(ka[3][e]); } \
    *(bf16x8*)(&(dst_)[(krow * 64 + kc + 8) ^ kswz]) = kb_; } while (0)
#define STAGE_V(dst_) do {                                                                       \
    _Pragma("unroll") for (int i = 0; i < 4; ++i)                                                \
    _Pragma("unroll") for (int e = 0; e < 4; ++e) {                                              \
      const int d_ = vd0 + i * 4 + e;                                                            \
      (dst_)[(d_ * 64 + vj) ^ ((d_ & 7) << 3)] = f2bf(va[i][e]); } } while (0)

  // =========================== phase 1: A(qt0) ===========================
  LOAD_KT(0); LOAD_VT(0);
  STAGE_K(kb0); STAGE_V(vb0);
  bar_lds();

  float l0 = 0.f;
#pragma unroll
  for (int dg = 0; dg < 4; ++dg) oacc[dg] = (f32x4){0.f, 0.f, 0.f, 0.f};

  for (int kt = 0; kt < NT0; ++kt) {
    short* const kbc = (kt & 1) ? kb1 : kb0;
    short* const vbc = (kt & 1) ? vb1 : vb0;
    if (kt + 1 < NT0) { LOAD_KT(kt + 1); LOAD_VT(kt + 1); }
    const bool diag = (kt == NT0 - 1);
#pragma unroll
    for (int jb = 0; jb < 4; ++jb) {
      bf16x8 kf0 = *(const bf16x8*)(&kbc[((jb * 16 + lr) * 64 + lg * 8) ^ asw]);
      bf16x8 kf1 = *(const bf16x8*)(&kbc[((jb * 16 + lr) * 64 + 32 + lg * 8) ^ asw]);
      f32x4 sA = {0.f, 0.f, 0.f, 0.f};
      sA = __builtin_amdgcn_mfma_f32_16x16x32_bf16(kf0, qf0[0], sA, 0, 0, 0);
      sA = __builtin_amdgcn_mfma_f32_16x16x32_bf16(kf1, qf0[1], sA, 0, 0, 0);
      short4 ps;
#pragma unroll
      for (int r = 0; r < 4; ++r) {
        const int jgl = kt * 64 + jb * 16 + lg * 4 + r;
        float pt = exp2_fast(sA[r]);
        if (diag && jgl > igl0) pt = 0.f;
        l0 += pt;
        ((short*)&ps)[r] = f2bf(pt);
      }
      *(short4*)(&psc[(lr * 64 + jb * 16 + lg * 4) ^ asw]) = ps;
    }
    __builtin_amdgcn_s_setprio(1);
#pragma unroll
    for (int ks = 0; ks < 2; ++ks) {
      bf16x8 pa = *(const bf16x8*)(&psc[(lr * 64 + ks * 32 + lg * 8) ^ asw]);
#pragma unroll
      for (int dg = 0; dg < 4; ++dg) {
        bf16x8 vv = *(const bf16x8*)(&vbc[((dg * 16 + lr) * 64 + ks * 32 + lg * 8) ^ asw]);
        oacc[dg] = __builtin_amdgcn_mfma_f32_16x16x32_bf16(pa, vv, oacc[dg], 0, 0, 0);
      }
    }
    __builtin_amdgcn_s_setprio(0);
    if (kt + 1 < NT0) {
      if (kt & 1) { STAGE_K(kb0); STAGE_V(vb0); } else { STAGE_K(kb1); STAGE_V(vb1); }
    }
    bar_lds();
  }

  l0 += __shfl_xor(l0, 16, 64);
  l0 += __shfl_xor(l0, 32, 64);
  const float rlA0 = 1.f / l0;  // per-lane: rl of row igl0
  {  // O0 write (rl bounce through per-wave psc; same-wave in-order LDS)
    float* const rlv = (float*)psc;
    if (lane < 16) rlv[lane] = rlA0;
    asm volatile("s_waitcnt lgkmcnt(0)" ::: "memory");
    float rr[4];
#pragma unroll
    for (int r = 0; r < 4; ++r) rr[r] = rlv[lg * 4 + r];
#pragma unroll
    for (int dg = 0; dg < 4; ++dg) {
#pragma unroll
      for (int r = 0; r < 4; ++r) {
        og[bh_off + (size_t)(qt0 * 64 + w * 16 + lg * 4 + r) * D + dg * 16 + lr] =
            oacc[dg][r] * rr[r];
      }
    }
  }

  // ================= phase 2: A(qt1) + piggybacked B(qt0) =================
  LOAD_KT(0); LOAD_VT(0);
  STAGE_K(kb0); STAGE_V(vb0);
  bar_lds();

  float l1 = 0.f;
#pragma unroll
  for (int dg = 0; dg < 4; ++dg) oacc[dg] = (f32x4){0.f, 0.f, 0.f, 0.f};

  for (int kt = 0; kt < NT1; ++kt) {
    short* const kbc = (kt & 1) ? kb1 : kb0;
    short* const vbc = (kt & 1) ? vb1 : vb0;
    if (kt + 1 < NT1) { LOAD_KT(kt + 1); LOAD_VT(kt + 1); }
    const bool diagA = (kt == NT1 - 1);
    const bool doB = (kt < NT0);
    const bool diagB = (kt == NT0 - 1);
#pragma unroll
    for (int jb = 0; jb < 4; ++jb) {
      bf16x8 kf0 = *(const bf16x8*)(&kbc[((jb * 16 + lr) * 64 + lg * 8) ^ asw]);
      bf16x8 kf1 = *(const bf16x8*)(&kbc[((jb * 16 + lr) * 64 + 32 + lg * 8) ^ asw]);
      f32x4 sA = {0.f, 0.f, 0.f, 0.f};
      sA = __builtin_amdgcn_mfma_f32_16x16x32_bf16(kf0, qf1[0], sA, 0, 0, 0);
      sA = __builtin_amdgcn_mfma_f32_16x16x32_bf16(kf1, qf1[1], sA, 0, 0, 0);
      short4 ps;
#pragma unroll
      for (int r = 0; r < 4; ++r) {
        const int jgl = kt * 64 + jb * 16 + lg * 4 + r;
        float pt = exp2_fast(sA[r]);
        if (diagA && jgl > igl1) pt = 0.f;
        l1 += pt;
        ((short*)&ps)[r] = f2bf(pt);
      }
      *(short4*)(&psc[(lr * 64 + jb * 16 + lg * 4) ^ asw]) = ps;
      if (doB) {  // B(qt0): same kf fragments, different Q operand -> free recompute
        f32x4 sB = {0.f, 0.f, 0.f, 0.f};
        sB = __builtin_amdgcn_mfma_f32_16x16x32_bf16(kf0, qf0[0], sB, 0, 0, 0);
        sB = __builtin_amdgcn_mfma_f32_16x16x32_bf16(kf1, qf0[1], sB, 0, 0, 0);
        f32x4 av;
#pragma unroll
        for (int r = 0; r < 4; ++r) {
          const int jgl = kt * 64 + jb * 16 + lg * 4 + r;
          float pt = exp2_fast(sB[r]);
          if (diagB && jgl > igl0) pt = 0.f;
          av[r] = pt * rlA0;
        }
        __builtin_nontemporal_store(av,
            (f32x4*)(a_base + (size_t)igl0 * S + kt * 64 + jb * 16 + lg * 4));
      }
    }
    __builtin_amdgcn_s_setprio(1);
#pragma unroll
    for (int ks = 0; ks < 2; ++ks) {
      bf16x8 pa = *(const bf16x8*)(&psc[(lr * 64 + ks * 32 + lg * 8) ^ asw]);
#pragma unroll
      for (int dg = 0; dg < 4; ++dg) {
        bf16x8 vv = *(const bf16x8*)(&vbc[((dg * 16 + lr) * 64 + ks * 32 + lg * 8) ^ asw]);
        oacc[dg] = __builtin_amdgcn_mfma_f32_16x16x32_bf16(pa, vv, oacc[dg], 0, 0, 0);
      }
    }
    __builtin_amdgcn_s_setprio(0);
    if (kt + 1 < NT1) {
      if (kt & 1) { STAGE_K(kb0); STAGE_V(vb0); } else { STAGE_K(kb1); STAGE_V(vb1); }
    }
    bar_lds();
  }

  l1 += __shfl_xor(l1, 16, 64);
  l1 += __shfl_xor(l1, 32, 64);
  const float rlA1 = 1.f / l1;
  {  // O1 write
    float* const rlv = (float*)psc;
    if (lane < 16) rlv[lane] = rlA1;
    asm volatile("s_waitcnt lgkmcnt(0)" ::: "memory");
    float rr[4];
#pragma unroll
    for (int r = 0; r < 4; ++r) rr[r] = rlv[lg * 4 + r];
#pragma unroll
    for (int dg = 0; dg < 4; ++dg) {
#pragma unroll
      for (int r = 0; r < 4; ++r) {
        og[bh_off + (size_t)(qt1 * 64 + w * 16 + lg * 4 + r) * D + dg * 16 + lr] =
            oacc[dg][r] * rr[r];
      }
    }
  }

  // ============ phase 3: standalone B(qt1) + all zero-fill ============
  LOAD_KT(0);
  STAGE_K(kb0);
  bar_lds();

  const f32x4 zz = {0.f, 0.f, 0.f, 0.f};
  for (int kt = 0; kt < S / 64; ++kt) {
    if (kt < NT1) {
      short* const kbc = (kt & 1) ? kb1 : kb0;
      if (kt + 1 < NT1) LOAD_KT(kt + 1);
      const bool diag = (kt == NT1 - 1);
#pragma unroll
      for (int jb = 0; jb < 4; ++jb) {
        bf16x8 kf0 = *(const bf16x8*)(&kbc[((jb * 16 + lr) * 64 + lg * 8) ^ asw]);
        bf16x8 kf1 = *(const bf16x8*)(&kbc[((jb * 16 + lr) * 64 + 32 + lg * 8) ^ asw]);
        f32x4 sB = {0.f, 0.f, 0.f, 0.f};
        sB = __builtin_amdgcn_mfma_f32_16x16x32_bf16(kf0, qf1[0], sB, 0, 0, 0);
        sB = __builtin_amdgcn_mfma_f32_16x16x32_bf16(kf1, qf1[1], sB, 0, 0, 0);
        f32x4 av;
#pragma unroll
        for (int r = 0; r < 4; ++r) {
          const int jgl = kt * 64 + jb * 16 + lg * 4 + r;
          float pt = exp2_fast(sB[r]);
          if (diag && jgl > igl1) pt = 0.f;
          av[r] = pt * rlA1;
        }
        __builtin_nontemporal_store(av,
            (f32x4*)(a_base + (size_t)igl1 * S + kt * 64 + jb * 16 + lg * 4));
      }
      if (kt + 1 < NT1) {
        if (kt & 1) STAGE_K(kb0); else STAGE_K(kb1);
      }
      bar_lds();
    }
    if (kt >= NT0) {  // qt0 rows are zero from tile NT0 on
#pragma unroll
      for (int jb = 0; jb < 4; ++jb) {
        __builtin_nontemporal_store(zz,
            (f32x4*)(a_base + (size_t)igl0 * S + kt * 64 + jb * 16 + lg * 4));
      }
    }
    if (kt >= NT1) {  // qt1 rows zero from tile NT1 on
#pragma unroll
      for (int jb = 0; jb < 4; ++jb) {
        __builtin_nontemporal_store(zz,
            (f32x4*)(a_base + (size_t)igl1 * S + kt * 64 + jb * 16 + lg * 4));
      }
    }
  }

#undef LOAD_KT
#undef LOAD_VT
#undef STAGE_K
#undef STAGE_V
}

extern "C" void kernel_launch(void* const* d_in, const int* in_sizes, int n_in,
                              void* d_out, int out_size, void* d_ws, size_t ws_size,
                              hipStream_t stream) {
  const float* q = (const float*)d_in[0];
  const float* k = (const float*)d_in[1];
  const float* v = (const float*)d_in[2];
  float* out = (float*)d_out;
  (void)hipFuncSetAttribute((const void*)attn_pair,
                            hipFuncAttributeMaxDynamicSharedMemorySize, SMEM_BYTES);
  attn_pair<<<dim3(1024), dim3(256), SMEM_BYTES, stream>>>(q, k, v, out);
}

// Round 10
// 348.293 us; speedup vs baseline: 1.3397x; 1.3397x over previous
//
#include <hip/hip_runtime.h>
#include <hip/hip_bf16.h>

namespace {
constexpr int S = 2048;
constexpr int D = 64;
constexpr float QSCALE = 0.18033688011112042f;  // (1/sqrt(64)) * log2(e)

using f32x4 = __attribute__((ext_vector_type(4))) float;
using bf16x8 = __attribute__((ext_vector_type(8))) short;

__device__ __forceinline__ short f2bf(float f) {
  return __builtin_bit_cast(short, __float2bfloat16(f));  // native RNE cvt
}
#if __has_builtin(__builtin_amdgcn_exp2f)
__device__ __forceinline__ float exp2_fast(float x) { return __builtin_amdgcn_exp2f(x); }
#else
__device__ __forceinline__ float exp2_fast(float x) { return exp2f(x); }
#endif

__device__ __forceinline__ void bar_lds() {  // lgkm-only barrier: vmem prefetch stays in flight
  asm volatile("s_waitcnt lgkmcnt(0)" ::: "memory");
  __builtin_amdgcn_s_barrier();
}
}  // namespace

// One block = (bh, 64 q-rows). Zero-fill FIRST (stores overlap everyone's loop A),
// then loop A: QK+exp-sum+PV; then loop B: QK recompute -> normalized a stream.
// 40KB LDS -> 4 blocks/CU.
__global__ __launch_bounds__(256, 4) void attn_fused(const float* __restrict__ qg,
                                                     const float* __restrict__ kg,
                                                     const float* __restrict__ vg,
                                                     float* __restrict__ outg) {
  __shared__ short kbuf[2][64 * 64];   // K[j][d] bf16, XOR-swizzled, dbuf
  __shared__ short vbuf[2][64 * 64];   // V^T[d][j] bf16, XOR-swizzled, dbuf
  __shared__ short pscr[4][16 * 64];   // per-wave p~ redistribution scratch

  const int tid = threadIdx.x;
  const int w = tid >> 6, lane = tid & 63, lg = lane >> 4, lr = lane & 15;

  // XCD-chunked block map + long/short qt interleave for co-resident balance
  const int u = blockIdx.x;
  const int logical = (u & 7) * 256 + (u >> 3);  // 2048 % 8 == 0
  const int bh = logical >> 5;
  const int uu = logical & 31;
  const int qt = (uu & 1) ? (31 - (uu >> 1)) : (uu >> 1);
  const int qrow0 = qt * 64;
  const int NT = qt + 1;

  const size_t bh_off = (size_t)bh * S * D;
  float* const og = outg;
  float* const a_base = outg + (size_t)64 * S * D + (size_t)bh * S * S;
  const int asw = (lr & 7) << 3;

  const int igl = qrow0 + w * 16 + lr;  // this lane's q-row (QK col i / p row)

  // ---- zero tiles (j >= NT*64) FIRST: fire-and-forget NT stores that the
  // write pipe drains while this block (and all others) runs loop A ----
  {
    float* const arow = a_base + (size_t)igl * S;
    const f32x4 z = {0.f, 0.f, 0.f, 0.f};
    for (int zt = NT; zt < S / 64; ++zt) {
#pragma unroll
      for (int jb = 0; jb < 4; ++jb) {
        __builtin_nontemporal_store(z, (f32x4*)(arow + zt * 64 + jb * 16 + lg * 4));
      }
    }
  }

  // ---- Q B-fragment (col i = lr-row of this wave, k = d), QSCALE folded ----
  bf16x8 qf[2];
#pragma unroll
  for (int kh = 0; kh < 2; ++kh) {
    const float* qp = qg + bh_off + (size_t)igl * D + kh * 32 + lg * 8;
    f32x4 x0 = *(const f32x4*)(qp);
    f32x4 x1 = *(const f32x4*)(qp + 4);
    bf16x8 f;
#pragma unroll
    for (int e = 0; e < 4; ++e) {
      f[e] = f2bf(x0[e] * QSCALE);
      f[e + 4] = f2bf(x1[e] * QSCALE);
    }
    qf[kh] = f;
  }

  const int krow = tid >> 2, kc = (tid & 3) * 16;
  const int kswz = (krow & 7) << 3;
  const int vj = tid & 63, vd0 = (tid >> 6) * 16;

  // =========================== loop A: l + O(unnormalized) ===========================
  f32x4 ka[4], va[4];
  {
    const float* kp = kg + bh_off + (size_t)krow * D + kc;
#pragma unroll
    for (int i = 0; i < 4; ++i) ka[i] = *(const f32x4*)(kp + i * 4);
    const float* vp = vg + bh_off + (size_t)vj * D + vd0;
#pragma unroll
    for (int i = 0; i < 4; ++i) va[i] = *(const f32x4*)(vp + i * 4);
  }
  {  // stage tile 0
    bf16x8 kb;
#pragma unroll
    for (int e = 0; e < 4; ++e) { kb[e] = f2bf(ka[0][e]); kb[e + 4] = f2bf(ka[1][e]); }
    *(bf16x8*)(&kbuf[0][(krow * 64 + kc) ^ kswz]) = kb;
#pragma unroll
    for (int e = 0; e < 4; ++e) { kb[e] = f2bf(ka[2][e]); kb[e + 4] = f2bf(ka[3][e]); }
    *(bf16x8*)(&kbuf[0][(krow * 64 + kc + 8) ^ kswz]) = kb;
#pragma unroll
    for (int i = 0; i < 4; ++i)
#pragma unroll
      for (int e = 0; e < 4; ++e) {
        const int d = vd0 + i * 4 + e;
        vbuf[0][(d * 64 + vj) ^ ((d & 7) << 3)] = f2bf(va[i][e]);
      }
  }
  bar_lds();

  float l_acc = 0.f;
  f32x4 oacc[4];
#pragma unroll
  for (int dg = 0; dg < 4; ++dg) oacc[dg] = (f32x4){0.f, 0.f, 0.f, 0.f};

  for (int kt = 0; kt < NT; ++kt) {
    const int cur = kt & 1;
    if (kt + 1 < NT) {  // prefetch next K/V tiles into regs
      const float* kp = kg + bh_off + (size_t)((kt + 1) * 64 + krow) * D + kc;
#pragma unroll
      for (int i = 0; i < 4; ++i) ka[i] = *(const f32x4*)(kp + i * 4);
      const float* vp = vg + bh_off + (size_t)((kt + 1) * 64 + vj) * D + vd0;
#pragma unroll
      for (int i = 0; i < 4; ++i) va[i] = *(const f32x4*)(vp + i * 4);
    }

    // QK^T: D[j][i], lane col i = lr, rows j = jb*16 + lg*4 + r
    f32x4 sacc[4];
#pragma unroll
    for (int jb = 0; jb < 4; ++jb) sacc[jb] = (f32x4){0.f, 0.f, 0.f, 0.f};
#pragma unroll
    for (int kh = 0; kh < 2; ++kh) {
#pragma unroll
      for (int jb = 0; jb < 4; ++jb) {
        bf16x8 kf = *(const bf16x8*)(&kbuf[cur][((jb * 16 + lr) * 64 + kh * 32 + lg * 8) ^ asw]);
        sacc[jb] = __builtin_amdgcn_mfma_f32_16x16x32_bf16(kf, qf[kh], sacc[jb], 0, 0, 0);
      }
    }

    // p~ = exp2(s) (masked on diagonal tile); accumulate l; pscr for PV
    const bool diag = (kt == NT - 1);
#pragma unroll
    for (int jb = 0; jb < 4; ++jb) {
      short4 ps;
#pragma unroll
      for (int r = 0; r < 4; ++r) {
        const int jgl = kt * 64 + jb * 16 + lg * 4 + r;
        float pt = exp2_fast(sacc[jb][r]);
        if (diag && jgl > igl) pt = 0.f;
        l_acc += pt;
        ((short*)&ps)[r] = f2bf(pt);
      }
      *(short4*)(&pscr[w][(lr * 64 + jb * 16 + lg * 4) ^ asw]) = ps;
    }

    // PV: O[i][d] += p~ V (pscr same-wave)
#pragma unroll
    for (int ks = 0; ks < 2; ++ks) {
      bf16x8 pa = *(const bf16x8*)(&pscr[w][(lr * 64 + ks * 32 + lg * 8) ^ asw]);
#pragma unroll
      for (int dg = 0; dg < 4; ++dg) {
        bf16x8 vb = *(const bf16x8*)(&vbuf[cur][((dg * 16 + lr) * 64 + ks * 32 + lg * 8) ^ asw]);
        oacc[dg] = __builtin_amdgcn_mfma_f32_16x16x32_bf16(pa, vb, oacc[dg], 0, 0, 0);
      }
    }

    if (kt + 1 < NT) {  // stage next tile into the other buffers
      bf16x8 kb;
#pragma unroll
      for (int e = 0; e < 4; ++e) { kb[e] = f2bf(ka[0][e]); kb[e + 4] = f2bf(ka[1][e]); }
      *(bf16x8*)(&kbuf[cur ^ 1][(krow * 64 + kc) ^ kswz]) = kb;
#pragma unroll
      for (int e = 0; e < 4; ++e) { kb[e] = f2bf(ka[2][e]); kb[e + 4] = f2bf(ka[3][e]); }
      *(bf16x8*)(&kbuf[cur ^ 1][(krow * 64 + kc + 8) ^ kswz]) = kb;
#pragma unroll
      for (int i = 0; i < 4; ++i)
#pragma unroll
        for (int e = 0; e < 4; ++e) {
          const int d = vd0 + i * 4 + e;
          vbuf[cur ^ 1][(d * 64 + vj) ^ ((d & 7) << 3)] = f2bf(va[i][e]);
        }
    }
    bar_lds();
  }

  // ---- rl: reduce partials across lg; lane then holds rl for its row igl ----
  l_acc += __shfl_xor(l_acc, 16, 64);
  l_acc += __shfl_xor(l_acc, 32, 64);
  const float rlA = 1.f / l_acc;

  // O rescale needs rl at rows w*16+lg*4+r: bounce via per-wave pscr region
  {
    float* const rlv = (float*)(&pscr[w][0]);
    if (lane < 16) rlv[lr] = rlA;
    asm volatile("s_waitcnt lgkmcnt(0)" ::: "memory");  // same-wave write->read
#pragma unroll
    for (int dg = 0; dg < 4; ++dg) {
#pragma unroll
      for (int r = 0; r < 4; ++r) {
        const int il = qrow0 + w * 16 + lg * 4 + r;
        og[bh_off + (size_t)il * D + dg * 16 + lr] = oacc[dg][r] * rlv[lg * 4 + r];
      }
    }
  }

  // =========================== loop B: stream normalized a ===========================
  float* const arow = a_base + (size_t)igl * S;
  {
    const float* kp = kg + bh_off + (size_t)krow * D + kc;
#pragma unroll
    for (int i = 0; i < 4; ++i) ka[i] = *(const f32x4*)(kp + i * 4);
  }
  {  // stage tile 0 (A-loop reads of kbuf[0] finished at A's last barrier)
    bf16x8 kb;
#pragma unroll
    for (int e = 0; e < 4; ++e) { kb[e] = f2bf(ka[0][e]); kb[e + 4] = f2bf(ka[1][e]); }
    *(bf16x8*)(&kbuf[0][(krow * 64 + kc) ^ kswz]) = kb;
#pragma unroll
    for (int e = 0; e < 4; ++e) { kb[e] = f2bf(ka[2][e]); kb[e + 4] = f2bf(ka[3][e]); }
    *(bf16x8*)(&kbuf[0][(krow * 64 + kc + 8) ^ kswz]) = kb;
  }
  bar_lds();

  for (int kt = 0; kt < NT; ++kt) {
    const int cur = kt & 1;
    if (kt + 1 < NT) {  // prefetch next K tile (issued BEFORE this tile's stores)
      const float* kp = kg + bh_off + (size_t)((kt + 1) * 64 + krow) * D + kc;
#pragma unroll
      for (int i = 0; i < 4; ++i) ka[i] = *(const f32x4*)(kp + i * 4);
    }

    f32x4 sacc[4];
#pragma unroll
    for (int jb = 0; jb < 4; ++jb) sacc[jb] = (f32x4){0.f, 0.f, 0.f, 0.f};
#pragma unroll
    for (int kh = 0; kh < 2; ++kh) {
#pragma unroll
      for (int jb = 0; jb < 4; ++jb) {
        bf16x8 kf = *(const bf16x8*)(&kbuf[cur][((jb * 16 + lr) * 64 + kh * 32 + lg * 8) ^ asw]);
        sacc[jb] = __builtin_amdgcn_mfma_f32_16x16x32_bf16(kf, qf[kh], sacc[jb], 0, 0, 0);
      }
    }

    const bool diag = (kt == NT - 1);
#pragma unroll
    for (int jb = 0; jb < 4; ++jb) {
      f32x4 av;
#pragma unroll
      for (int r = 0; r < 4; ++r) {
        const int jgl = kt * 64 + jb * 16 + lg * 4 + r;
        float pt = exp2_fast(sacc[jb][r]);
        if (diag && jgl > igl) pt = 0.f;
        av[r] = pt * rlA;
      }
      __builtin_nontemporal_store(av, (f32x4*)(arow + kt * 64 + jb * 16 + lg * 4));
    }

    if (kt + 1 < NT) {
      bf16x8 kb;
#pragma unroll
      for (int e = 0; e < 4; ++e) { kb[e] = f2bf(ka[0][e]); kb[e + 4] = f2bf(ka[1][e]); }
      *(bf16x8*)(&kbuf[cur ^ 1][(krow * 64 + kc) ^ kswz]) = kb;
#pragma unroll
      for (int e = 0; e < 4; ++e) { kb[e] = f2bf(ka[2][e]); kb[e + 4] = f2bf(ka[3][e]); }
      *(bf16x8*)(&kbuf[cur ^ 1][(krow * 64 + kc + 8) ^ kswz]) = kb;
    }
    bar_lds();
  }
}

extern "C" void kernel_launch(void* const* d_in, const int* in_sizes, int n_in,
                              void* d_out, int out_size, void* d_ws, size_t ws_size,
                              hipStream_t stream) {
  const float* q = (const float*)d_in[0];
  const float* k = (const float*)d_in[1];
  const float* v = (const float*)d_in[2];
  float* out = (float*)d_out;
  attn_fused<<<dim3(2048), dim3(256), 0, stream>>>(q, k, v, out);
}